// Round 2
// baseline (1311.638 us; speedup 1.0000x reference)
//
#include <hip/hip_runtime.h>
#include <math.h>

// V = 1e6 nodes, D = 256, B = 32768 graphs. batch is SORTED -> contiguous segments.
// Wb dropped (uniform shift cancels in softmax). seg_max dropped (cancels exactly in
// the ratio; scores ~ N(0,1) so fp32 exp is safe).
//
// Round-2 restructure: persistent-wave streaming segmented reduction.
// 4096 waves total (1024 blocks x 4 waves), each wave owns SEGS_PER_WAVE=8
// CONSECUTIVE segments = one contiguous ~244-row slab of H. The row stream never
// stops at segment boundaries (only wave-uniform finalize/reset bookkeeping),
// so each wave is one long sequential HBM stream with a steady 2-deep prefetch
// pipeline, instead of 32768 short-lived waves paying startup latency each.
// All row buffers are named scalars (no arrays -> no scratch risk).

#define DIM 256
#define LANES 64
#define CHUNK 8
#define SEGS_PER_WAVE 8
#define WAVES_PER_BLOCK 4

// Kernel 1: segment boundaries via lower_bound on sorted batch.
__global__ void seg_bounds_kernel(const int* __restrict__ batch, int V, int B,
                                  int* __restrict__ seg_start) {
    int b = blockIdx.x * blockDim.x + threadIdx.x;
    if (b > B) return;
    int lo = 0, hi = V;
    while (lo < hi) {
        int mid = (lo + hi) >> 1;
        if (batch[mid] < b) lo = mid + 1; else hi = mid;
    }
    seg_start[b] = lo;
}

#define DOT4(h_) ((h_).x * w.x + (h_).y * w.y + (h_).z * w.z + (h_).w * w.w)

#define BFLY8(off_) do {                                                     \
    p0 += __shfl_xor(p0, off_, 64); p1 += __shfl_xor(p1, off_, 64);          \
    p2 += __shfl_xor(p2, off_, 64); p3 += __shfl_xor(p3, off_, 64);          \
    p4 += __shfl_xor(p4, off_, 64); p5 += __shfl_xor(p5, off_, 64);          \
    p6 += __shfl_xor(p6, off_, 64); p7 += __shfl_xor(p7, off_, 64);          \
} while (0)

// Finalize current local segment: write acc/l (zeros if empty), reset, advance.
// r, se, cur are wave-uniform -> uniform branch. bnd[lane>segN] = INT_MAX, so the
// se refresh is always a defined lane read (index <= segN+1 <= 9 < 64).
#define FINALIZE_SEG() do {                                                  \
    float inv_ = (l > 0.0f) ? (1.0f / l) : 0.0f;                             \
    float4 o_;                                                               \
    o_.x = acc.x * inv_; o_.y = acc.y * inv_;                                \
    o_.z = acc.z * inv_; o_.w = acc.w * inv_;                                \
    out4[(size_t)(seg0 + cur) * LANES + lane] = o_;                          \
    acc.x = 0.0f; acc.y = 0.0f; acc.z = 0.0f; acc.w = 0.0f; l = 0.0f;        \
    ++cur; se = __shfl(bnd, cur + 1, 64);                                    \
} while (0)

// Consume one row (score already broadcast, e = exp(score)): advance segment
// bookkeeping past any boundaries (handles empty segments), then accumulate.
#define ROWSTEP(hk_, ek_) do {                                               \
    while (r >= se) FINALIZE_SEG();                                          \
    l += (ek_);                                                              \
    acc.x += (ek_) * (hk_).x; acc.y += (ek_) * (hk_).y;                      \
    acc.z += (ek_) * (hk_).z; acc.w += (ek_) * (hk_).w;                      \
    ++r;                                                                     \
} while (0)

#define LOAD8(h0_,h1_,h2_,h3_,h4_,h5_,h6_,h7_, rowoff_) do {                 \
    const float4* q_ = hp + (size_t)(rowoff_) * LANES;                       \
    h0_ = q_[0 * LANES]; h1_ = q_[1 * LANES];                                \
    h2_ = q_[2 * LANES]; h3_ = q_[3 * LANES];                                \
    h4_ = q_[4 * LANES]; h5_ = q_[5 * LANES];                                \
    h6_ = q_[6 * LANES]; h7_ = q_[7 * LANES];                                \
} while (0)

#define PROC8(h0_,h1_,h2_,h3_,h4_,h5_,h6_,h7_) do {                          \
    float p0 = DOT4(h0_), p1 = DOT4(h1_), p2 = DOT4(h2_), p3 = DOT4(h3_);    \
    float p4 = DOT4(h4_), p5 = DOT4(h5_), p6 = DOT4(h6_), p7 = DOT4(h7_);    \
    BFLY8(32); BFLY8(16); BFLY8(8); BFLY8(4); BFLY8(2); BFLY8(1);            \
    const float e0 = __expf(p0), e1 = __expf(p1);                            \
    const float e2 = __expf(p2), e3 = __expf(p3);                            \
    const float e4 = __expf(p4), e5 = __expf(p5);                            \
    const float e6 = __expf(p6), e7 = __expf(p7);                            \
    ROWSTEP(h0_, e0); ROWSTEP(h1_, e1); ROWSTEP(h2_, e2); ROWSTEP(h3_, e3);  \
    ROWSTEP(h4_, e4); ROWSTEP(h5_, e5); ROWSTEP(h6_, e6); ROWSTEP(h7_, e7);  \
} while (0)

// Kernel 2: persistent waves; each wave streams the contiguous row range of its
// 8 consecutive segments. Lane i owns dims [4i,4i+4) -> 1KB coalesced per row.
__launch_bounds__(256)
__global__ void attn_agg_kernel(const float* __restrict__ H,
                                const float* __restrict__ Ww,
                                const int* __restrict__ seg_start,
                                float* __restrict__ out, int B) {
    const int wave = threadIdx.x >> 6;
    const int lane = threadIdx.x & 63;
    const int gw   = blockIdx.x * WAVES_PER_BLOCK + wave;
    const int seg0 = gw * SEGS_PER_WAVE;
    if (seg0 >= B) return;
    const int segN = (B - seg0 < SEGS_PER_WAVE) ? (B - seg0) : SEGS_PER_WAVE;

    // lane j (j <= segN) holds boundary seg_start[seg0 + j]; others +inf.
    int bnd = 0x7fffffff;
    if (lane <= segN) bnd = seg_start[seg0 + lane];

    const int v0   = __shfl(bnd, 0, 64);
    const int vend = __shfl(bnd, segN, 64);

    const float4* __restrict__ H4 = (const float4*)H;
    const float4 w = ((const float4*)Ww)[lane];
    float4* __restrict__ out4 = (float4*)out;
    const float4* __restrict__ hp = H4 + (size_t)v0 * LANES + lane;

    float  l   = 0.0f;
    float4 acc = make_float4(0.f, 0.f, 0.f, 0.f);
    int cur = 0;                        // local segment index in [0, segN)
    int se  = __shfl(bnd, 1, 64);       // end row (exclusive) of current segment
    int r   = v0;                       // row cursor (global)

    const int nrows = vend - v0;
    const int nfull = nrows >> 3;

    float4 a0,a1,a2,a3,a4,a5,a6,a7;
    float4 b0,b1,b2,b3,b4,b5,b6,b7;

    if (nfull > 0) {
        LOAD8(a0,a1,a2,a3,a4,a5,a6,a7, 0);
        int i = 0;
        for (; i + 2 <= nfull; i += 2) {
            LOAD8(b0,b1,b2,b3,b4,b5,b6,b7, (i + 1) * CHUNK);   // prefetch i+1
            PROC8(a0,a1,a2,a3,a4,a5,a6,a7);
            if (i + 2 < nfull)
                LOAD8(a0,a1,a2,a3,a4,a5,a6,a7, (i + 2) * CHUNK); // prefetch i+2
            PROC8(b0,b1,b2,b3,b4,b5,b6,b7);
        }
        if (i < nfull) PROC8(a0,a1,a2,a3,a4,a5,a6,a7);
    }

    // tail: < 8 rows, one at a time
    for (; r < vend; ) {
        float4 h = hp[(size_t)(r - v0) * LANES];
        float p = DOT4(h);
        p += __shfl_xor(p, 32, 64); p += __shfl_xor(p, 16, 64);
        p += __shfl_xor(p,  8, 64); p += __shfl_xor(p,  4, 64);
        p += __shfl_xor(p,  2, 64); p += __shfl_xor(p,  1, 64);
        const float e = __expf(p);
        ROWSTEP(h, e);
    }

    // finalize last segment + trailing empty segments
    while (cur < segN) FINALIZE_SEG();
}

extern "C" void kernel_launch(void* const* d_in, const int* in_sizes, int n_in,
                              void* d_out, int out_size, void* d_ws, size_t ws_size,
                              hipStream_t stream) {
    const float* H     = (const float*)d_in[0];
    const int*   batch = (const int*)d_in[1];
    const float* Ww    = (const float*)d_in[2];
    // d_in[3] (Wb) unused: uniform score shift cancels in softmax.

    const int V = in_sizes[1];
    const int B = out_size / DIM;

    int* seg_start = (int*)d_ws;   // (B+1) ints

    {
        int n = B + 1;
        int threads = 256;
        int blocks = (n + threads - 1) / threads;
        seg_bounds_kernel<<<blocks, threads, 0, stream>>>(batch, V, B, seg_start);
    }
    {
        const int segs_per_block = WAVES_PER_BLOCK * SEGS_PER_WAVE;   // 32
        int threads = 256;
        int blocks = (B + segs_per_block - 1) / segs_per_block;       // 1024
        attn_agg_kernel<<<blocks, threads, 0, stream>>>(H, Ww, seg_start, (float*)d_out, B);
    }
}